// Round 4
// baseline (116.212 us; speedup 1.0000x reference)
//
#include <hip/hip_runtime.h>
#include <math.h>

#define Bsz 2048
#define Ddim 32
#define Nsz 8192
#define Kk 30
#define TPB 256
#define ROWS 4                    // rows (i) per block
#define JSL 2                     // j-dimension slices
#define JTILE (Bsz / JSL)         // 1024 j's per block
#define JCH (JTILE / TPB)         // 4 chunks per thread
#define NBLK ((Bsz / ROWS) * JSL) // 1024 blocks = 4 blocks/CU, fully resident
#define NW (Nsz / 32)             // 256 bitset words per row

// Latency-hiding via TLP, not registers: z_i stays in LDS (block-uniform ->
// broadcast ds_read_b128, conflict-free, LDS pipe overlaps VALU), no explicit
// global double-buffer. VGPR ~95 -> __launch_bounds__(256,4) -> 4 blocks/CU
// -> whole grid resident in one round, no tail.
__global__ __launch_bounds__(TPB, 4) void softnp_main(
    const float* __restrict__ z,
    const int*   __restrict__ pre_knn,
    const int*   __restrict__ samp,
    float*       __restrict__ wsden,   // [JSL][Bsz] partial denominators
    float*       __restrict__ wsnum)   // [JSL][Bsz] partial masked numerators
{
    __shared__ unsigned bits4[NW][ROWS];   // 4 KB, word-interleaved by row
    __shared__ int      sampsh[JTILE];     // 4 KB
    __shared__ float    zish[ROWS * Ddim]; // 512 B
    __shared__ int      rowsi[ROWS];
    __shared__ float    rden[4][ROWS], rnum[4][ROWS];

    const int t  = threadIdx.x;
    const int rg = blockIdx.x >> 1;
    const int sl = blockIdx.x & 1;
    const int i0 = rg * ROWS;
    const int jb = sl * JTILE;

    // ---- stage: zero bitsets, slice of samp -> LDS, z_i -> LDS ----
    #pragma unroll
    for (int c = 0; c < (NW * ROWS) / TPB; ++c)
        ((unsigned*)bits4)[t + c * TPB] = 0u;
    #pragma unroll
    for (int c = 0; c < JCH; ++c)
        sampsh[t + c * TPB] = samp[jb + t + c * TPB];
    if (t < ROWS * Ddim) zish[t] = z[(size_t)i0 * Ddim + t];
    if (t < ROWS) rowsi[t] = samp[i0 + t];
    __syncthreads();

    // ---- fill bitsets: 4 rows x 30 entries ----
    if (t < ROWS * 32) {
        const int r = t >> 5, k = t & 31;
        if (k < Kk) {
            const int id = pre_knn[(size_t)rowsi[r] * Kk + k];
            atomicOr(&bits4[id >> 5][r], 1u << (id & 31));
        }
    }
    __syncthreads();

    // ---- |z_i|^2 per row (from LDS broadcast reads) ----
    const float4* z4 = (const float4*)zish;
    float si2[ROWS];
    #pragma unroll
    for (int r = 0; r < ROWS; ++r) {
        float s = 0.f;
        #pragma unroll
        for (int d = 0; d < Ddim / 4; ++d) {
            const float4 a = z4[r * (Ddim / 4) + d];
            s += a.x * a.x + a.y * a.y + a.z * a.z + a.w * a.w;
        }
        si2[r] = s;
    }

    float den[ROWS] = {0.f, 0.f, 0.f, 0.f};
    float num[ROWS] = {0.f, 0.f, 0.f, 0.f};

    // ---- single-pass j loop; z_i re-read from LDS (broadcast) per chunk ----
    const float4* zg = (const float4*)z;
    #pragma unroll
    for (int c = 0; c < JCH; ++c) {
        const int j = jb + t + c * TPB;

        float4 cur[8];
        #pragma unroll
        for (int d = 0; d < 8; ++d) cur[d] = zg[(size_t)j * 8 + d];

        float dot[ROWS] = {0.f, 0.f, 0.f, 0.f};
        float sj2 = 0.f;
        #pragma unroll
        for (int d = 0; d < 8; ++d) {
            const float4 v = cur[d];
            sj2 += v.x * v.x + v.y * v.y + v.z * v.z + v.w * v.w;
            #pragma unroll
            for (int r = 0; r < ROWS; ++r) {
                const float4 a = z4[r * 8 + d];   // LDS broadcast read
                dot[r] += a.x * v.x + a.y * v.y + a.z * v.z + a.w * v.w;
            }
        }

        const int   sj = sampsh[t + c * TPB];
        const uint4 bw = ((const uint4*)bits4)[sj >> 5]; // 4 rows, 1 ds_read_b128
        const unsigned bsel[4] = {bw.x, bw.y, bw.z, bw.w};
        #pragma unroll
        for (int r = 0; r < ROWS; ++r) {
            const float d2 = fmaxf(si2[r] + sj2 - 2.f * dot[r], 0.f);
            const bool diag = (j == i0 + r);
            const float e = diag ? 0.f : __expf(-sqrtf(d2));
            den[r] += e;
            if (!diag && ((bsel[r] >> (sj & 31)) & 1u)) num[r] += e;
        }
    }

    // ---- wave shuffle reduction (no barriers), 4-wave LDS combine ----
    const int lane = t & 63, wv = t >> 6;
    #pragma unroll
    for (int r = 0; r < ROWS; ++r) {
        #pragma unroll
        for (int off = 32; off > 0; off >>= 1) {
            den[r] += __shfl_xor(den[r], off, 64);
            num[r] += __shfl_xor(num[r], off, 64);
        }
    }
    if (lane == 0) {
        #pragma unroll
        for (int r = 0; r < ROWS; ++r) { rden[wv][r] = den[r]; rnum[wv][r] = num[r]; }
    }
    __syncthreads();

    if (t < ROWS) {
        float D = 0.f, Nm = 0.f;
        #pragma unroll
        for (int w = 0; w < 4; ++w) { D += rden[w][t]; Nm += rnum[w][t]; }
        wsden[sl * Bsz + i0 + t] = D;   // pure overwrite: no zero-init needed
        wsnum[sl * Bsz + i0 + t] = Nm;
    }
}

__global__ __launch_bounds__(TPB) void softnp_final(
    const float* __restrict__ wsden,
    const float* __restrict__ wsnum,
    float*       __restrict__ out)
{
    __shared__ float rl[4], rc[4];
    const int t = threadIdx.x;
    float loss = 0.f, vcnt = 0.f;
    #pragma unroll
    for (int c = 0; c < Bsz / TPB; ++c) {
        const int r = t + c * TPB;
        const float D  = wsden[r] + wsden[Bsz + r];
        const float Nm = wsnum[r] + wsnum[Bsz + r];
        if (Nm > 0.f) {             // valid <=> any masked neighbor (no underflow)
            loss -= __logf(Nm / D + 1e-8f);
            vcnt += 1.f;
        }
    }
    #pragma unroll
    for (int off = 32; off > 0; off >>= 1) {
        loss += __shfl_xor(loss, off, 64);
        vcnt += __shfl_xor(vcnt, off, 64);
    }
    const int lane = t & 63, wv = t >> 6;
    if (lane == 0) { rl[wv] = loss; rc[wv] = vcnt; }
    __syncthreads();
    if (t == 0) {
        const float L = rl[0] + rl[1] + rl[2] + rl[3];
        const float C = rc[0] + rc[1] + rc[2] + rc[3];
        out[0] = (C > 0.f) ? L / C : 0.f;
    }
}

extern "C" void kernel_launch(void* const* d_in, const int* in_sizes, int n_in,
                              void* d_out, int out_size, void* d_ws, size_t ws_size,
                              hipStream_t stream)
{
    const float* z       = (const float*)d_in[0];
    const int*   pre_knn = (const int*)d_in[1];
    const int*   samp    = (const int*)d_in[2];
    float*       out     = (float*)d_out;
    float*       wsden   = (float*)d_ws;             // [JSL][Bsz]
    float*       wsnum   = wsden + JSL * Bsz;        // [JSL][Bsz]

    softnp_main<<<dim3(NBLK), dim3(TPB), 0, stream>>>(z, pre_knn, samp, wsden, wsnum);
    softnp_final<<<dim3(1), dim3(TPB), 0, stream>>>(wsden, wsnum, out);
}

// Round 5
// 93.877 us; speedup vs baseline: 1.2379x; 1.2379x over previous
//
#include <hip/hip_runtime.h>
#include <math.h>

#define Bsz 2048
#define Ddim 32
#define Nsz 8192
#define Kk 30
#define TPB 256
#define ROWS 2                    // rows per block; z_i lives in SGPRs
#define NBLK (Bsz / ROWS)         // 1024 blocks, ~4-5/CU, fully resident
#define JCH (Bsz / TPB)           // 8 chunks: each block covers ALL j
#define NW (Nsz / 32)             // 256 bitset words per row

// R4 post-mortem: LDS-broadcast zi gets hoisted by the compiler -> 128 VGPR
// + launch_bounds squeeze -> scratch spills (77 MB writes). Fix: zi is
// BLOCK-UNIFORM, so pin it to SGPRs via readfirstlane (v_fma takes one SGPR
// operand). ROWS=2 -> 64 SGPR of zi, VGPR ~100 -> 4-5 waves/SIMD, grid
// resident in one round.
__device__ __forceinline__ float rfl(float x) {
    return __uint_as_float(__builtin_amdgcn_readfirstlane(__float_as_uint(x)));
}

__global__ __launch_bounds__(TPB, 3) void softnp_main(
    const float* __restrict__ z,
    const int*   __restrict__ pre_knn,
    const int*   __restrict__ samp,
    float*       __restrict__ wsden,   // [Bsz] denominators
    float*       __restrict__ wsnum)   // [Bsz] masked numerators
{
    __shared__ unsigned bits2[NW][ROWS];   // 2 KB, word-interleaved by row
    __shared__ int      sampsh[Bsz];       // 8 KB
    __shared__ float    zish[ROWS * Ddim]; // 256 B
    __shared__ int      rowsi[ROWS];
    __shared__ float    rden[4][ROWS], rnum[4][ROWS];

    const int t  = threadIdx.x;
    const int i0 = blockIdx.x * ROWS;

    // ---- stage: zero bitsets, samp -> LDS, z_i -> LDS ----
    #pragma unroll
    for (int c = 0; c < (NW * ROWS) / TPB; ++c)
        ((unsigned*)bits2)[t + c * TPB] = 0u;
    #pragma unroll
    for (int c = 0; c < JCH; ++c)
        sampsh[t + c * TPB] = samp[t + c * TPB];
    if (t < ROWS * Ddim) zish[t] = z[(size_t)i0 * Ddim + t];
    if (t < ROWS) rowsi[t] = samp[i0 + t];
    __syncthreads();

    // ---- fill bitsets: 2 rows x 30 entries ----
    if (t < ROWS * 32) {
        const int r = t >> 5, k = t & 31;
        if (k < Kk) {
            const int id = pre_knn[(size_t)rowsi[r] * Kk + k];
            atomicOr(&bits2[id >> 5][r], 1u << (id & 31));
        }
    }
    __syncthreads();

    // ---- z_i into SGPRs (uniform across block) + |z_i|^2 ----
    float zis[ROWS][Ddim];
    #pragma unroll
    for (int r = 0; r < ROWS; ++r)
        #pragma unroll
        for (int d = 0; d < Ddim; ++d)
            zis[r][d] = rfl(zish[r * Ddim + d]);

    float si2[ROWS];
    #pragma unroll
    for (int r = 0; r < ROWS; ++r) {
        float s = 0.f;
        #pragma unroll
        for (int d = 0; d < Ddim; ++d) s += zis[r][d] * zis[r][d];
        si2[r] = rfl(s);
    }

    float den[ROWS] = {0.f, 0.f};
    float num[ROWS] = {0.f, 0.f};

    // ---- single-pass j loop over ALL 2048 j, double-buffered loads ----
    const float4* zg = (const float4*)z;
    int j = t;
    float4 cur[8];
    #pragma unroll
    for (int d = 0; d < 8; ++d) cur[d] = zg[(size_t)j * 8 + d];

    #pragma unroll
    for (int c = 0; c < JCH; ++c) {
        float4 nxt[8];
        if (c + 1 < JCH) {
            #pragma unroll
            for (int d = 0; d < 8; ++d) nxt[d] = zg[(size_t)(j + TPB) * 8 + d];
        }

        float dot[ROWS] = {0.f, 0.f};
        float sj2 = 0.f;
        #pragma unroll
        for (int d = 0; d < 8; ++d) {
            const float4 v = cur[d];
            sj2 += v.x * v.x + v.y * v.y + v.z * v.z + v.w * v.w;
            #pragma unroll
            for (int r = 0; r < ROWS; ++r)
                dot[r] += zis[r][4 * d + 0] * v.x + zis[r][4 * d + 1] * v.y
                        + zis[r][4 * d + 2] * v.z + zis[r][4 * d + 3] * v.w;
        }

        const int   sj = sampsh[j];
        const uint2 bw = ((const uint2*)bits2)[sj >> 5]; // 2 rows, 1 ds_read_b64
        const unsigned bsel[2] = {bw.x, bw.y};
        #pragma unroll
        for (int r = 0; r < ROWS; ++r) {
            const float d2 = fmaxf(si2[r] + sj2 - 2.f * dot[r], 0.f);
            const bool diag = (j == i0 + r);
            const float e = diag ? 0.f : __expf(-sqrtf(d2));
            den[r] += e;
            if (!diag && ((bsel[r] >> (sj & 31)) & 1u)) num[r] += e;
        }

        if (c + 1 < JCH) {
            #pragma unroll
            for (int d = 0; d < 8; ++d) cur[d] = nxt[d];
        }
        j += TPB;
    }

    // ---- wave shuffle reduction, 4-wave LDS combine ----
    const int lane = t & 63, wv = t >> 6;
    #pragma unroll
    for (int r = 0; r < ROWS; ++r) {
        #pragma unroll
        for (int off = 32; off > 0; off >>= 1) {
            den[r] += __shfl_xor(den[r], off, 64);
            num[r] += __shfl_xor(num[r], off, 64);
        }
    }
    if (lane == 0) {
        #pragma unroll
        for (int r = 0; r < ROWS; ++r) { rden[wv][r] = den[r]; rnum[wv][r] = num[r]; }
    }
    __syncthreads();

    if (t < ROWS) {
        float D = 0.f, Nm = 0.f;
        #pragma unroll
        for (int w = 0; w < 4; ++w) { D += rden[w][t]; Nm += rnum[w][t]; }
        wsden[i0 + t] = D;   // pure overwrite: no zero-init needed
        wsnum[i0 + t] = Nm;
    }
}

__global__ __launch_bounds__(TPB) void softnp_final(
    const float* __restrict__ wsden,
    const float* __restrict__ wsnum,
    float*       __restrict__ out)
{
    __shared__ float rl[4], rc[4];
    const int t = threadIdx.x;
    float loss = 0.f, vcnt = 0.f;
    #pragma unroll
    for (int c = 0; c < Bsz / TPB; ++c) {
        const int r = t + c * TPB;
        const float D  = wsden[r];
        const float Nm = wsnum[r];
        if (Nm > 0.f) {             // valid <=> any masked neighbor (no underflow)
            loss -= __logf(Nm / D + 1e-8f);
            vcnt += 1.f;
        }
    }
    #pragma unroll
    for (int off = 32; off > 0; off >>= 1) {
        loss += __shfl_xor(loss, off, 64);
        vcnt += __shfl_xor(vcnt, off, 64);
    }
    const int lane = t & 63, wv = t >> 6;
    if (lane == 0) { rl[wv] = loss; rc[wv] = vcnt; }
    __syncthreads();
    if (t == 0) {
        const float L = rl[0] + rl[1] + rl[2] + rl[3];
        const float C = rc[0] + rc[1] + rc[2] + rc[3];
        out[0] = (C > 0.f) ? L / C : 0.f;
    }
}

extern "C" void kernel_launch(void* const* d_in, const int* in_sizes, int n_in,
                              void* d_out, int out_size, void* d_ws, size_t ws_size,
                              hipStream_t stream)
{
    const float* z       = (const float*)d_in[0];
    const int*   pre_knn = (const int*)d_in[1];
    const int*   samp    = (const int*)d_in[2];
    float*       out     = (float*)d_out;
    float*       wsden   = (float*)d_ws;        // [Bsz]
    float*       wsnum   = wsden + Bsz;         // [Bsz]

    softnp_main<<<dim3(NBLK), dim3(TPB), 0, stream>>>(z, pre_knn, samp, wsden, wsnum);
    softnp_final<<<dim3(1), dim3(TPB), 0, stream>>>(wsden, wsnum, out);
}